// Round 2
// baseline (673.185 us; speedup 1.0000x reference)
//
#include <hip/hip_runtime.h>

// Problem dims
#define B_  2
#define S_  2048
#define E_  2048
#define H_  16
#define HD_ 128
#define M_  (B_*S_)    // 4096 rows of activations
#define N1_ (3*E_)     // 6144 qkv outputs
#define K_  E_         // 2048 reduction dim

typedef _Float16 f16;
typedef __attribute__((ext_vector_type(8))) _Float16 f16x8;
typedef __attribute__((ext_vector_type(4))) _Float16 f16x4;
typedef __attribute__((ext_vector_type(4))) float    f32x4;
typedef __attribute__((ext_vector_type(4))) float    fv4;

// ---------------------------------------------------------------- fp32->fp16
__global__ void cvt_f32_f16(const float* __restrict__ src, f16* __restrict__ dst, int n4) {
    int i = blockIdx.x * blockDim.x + threadIdx.x;
    if (i < n4) {
        fv4 v = ((const fv4*)src)[i];
        f16x4 h;
        h.x = (f16)v.x; h.y = (f16)v.y; h.z = (f16)v.z; h.w = (f16)v.w;
        ((f16x4*)dst)[i] = h;
    }
}

// XOR-swizzled LDS granule offset (8-half = 16B granules), BK=64 rows (8 granules)
__device__ __forceinline__ int swz8(int row, int g) {
    return row * 64 + ((g ^ (row & 7)) << 3);
}
// 128-half rows (16 granules)
__device__ __forceinline__ int swz16(int row, int g) {
    return row * 128 + ((g ^ (row & 15)) << 3);
}

// split 8 fp32 into fp16 hi + lo (x = hi + lo, residual ~2^-22 rel)
__device__ __forceinline__ void split8(fv4 a0, fv4 a1, float scale, f16x8& hi, f16x8& lo) {
    float x[8] = {a0.x, a0.y, a0.z, a0.w, a1.x, a1.y, a1.z, a1.w};
#pragma unroll
    for (int e = 0; e < 8; ++e) {
        float xs = x[e] * scale;
        f16 h = (f16)xs;
        hi[e] = h;
        lo[e] = (f16)(xs - (float)h);
    }
}

// ---------------------------------------------------------------- GEMM1: qkv = query @ Wqkv^T + bqkv
// fp32 inputs, split-fp16 (hi+lo) MFMA for q/k output tiles, hi-only for v tiles.
// W pre-scaled by 64 so W_lo stays fp16-normal; epilogue multiplies by 1/64.
// Epilogue scatters to head-major q/k and transposed vT.
__global__ __launch_bounds__(256) void gemm_qkv(
    const float* __restrict__ A, const float* __restrict__ W, const float* __restrict__ bias,
    f16* __restrict__ qh, f16* __restrict__ kh, f16* __restrict__ vT)
{
    __shared__ f16 As_hi[128 * 64];
    __shared__ f16 As_lo[128 * 64];
    __shared__ f16 Bs_hi[128 * 64];
    __shared__ f16 Bs_lo[128 * 64];
    const int t = threadIdx.x;
    const int w = t >> 6, lane = t & 63, quad = lane >> 4, l15 = lane & 15;
    const int m0 = blockIdx.y * 128, n0 = blockIdx.x * 128;
    const int wm = (w & 1) * 64, wn = (w >> 1) * 64;
    // 384 = 3*128: each 128-wide n-tile is entirely q (0), k (1), or v (2)
    const int tile_part = (n0 % 384) >> 7;
    const bool need_lo = (tile_part != 2);   // v columns don't feed softmax

    f32x4 acc[4][4];
#pragma unroll
    for (int i = 0; i < 4; ++i)
#pragma unroll
        for (int j = 0; j < 4; ++j) { acc[i][j].x = 0.f; acc[i][j].y = 0.f; acc[i][j].z = 0.f; acc[i][j].w = 0.f; }

    for (int kb = 0; kb < K_ / 64; ++kb) {
        const float* Ag = A + (size_t)m0 * K_ + kb * 64;
        const float* Bg = W + (size_t)n0 * K_ + kb * 64;
#pragma unroll
        for (int i = 0; i < 4; ++i) {
            int gid = t + i * 256;           // granule id 0..1023
            int row = gid >> 3, g = gid & 7;
            const float* ap = Ag + (size_t)row * K_ + g * 8;
            fv4 a0 = *(const fv4*)ap;
            fv4 a1 = *(const fv4*)(ap + 4);
            f16x8 hi, lo;
            split8(a0, a1, 1.0f, hi, lo);
            *(f16x8*)&As_hi[swz8(row, g)] = hi;
            *(f16x8*)&As_lo[swz8(row, g)] = lo;
            const float* bp = Bg + (size_t)row * K_ + g * 8;
            fv4 b0 = *(const fv4*)bp;
            fv4 b1 = *(const fv4*)(bp + 4);
            split8(b0, b1, 64.0f, hi, lo);
            *(f16x8*)&Bs_hi[swz8(row, g)] = hi;
            *(f16x8*)&Bs_lo[swz8(row, g)] = lo;
        }
        __syncthreads();
#pragma unroll
        for (int ks = 0; ks < 2; ++ks) {
            f16x8 ah[4], al[4], bh[4], bl[4];
            int g = ks * 4 + quad;
#pragma unroll
            for (int mt = 0; mt < 4; ++mt) {
                int row = wm + mt * 16 + l15;
                ah[mt] = *(const f16x8*)&As_hi[swz8(row, g)];
                al[mt] = *(const f16x8*)&As_lo[swz8(row, g)];
            }
#pragma unroll
            for (int nt = 0; nt < 4; ++nt) {
                int row = wn + nt * 16 + l15;
                bh[nt] = *(const f16x8*)&Bs_hi[swz8(row, g)];
                bl[nt] = *(const f16x8*)&Bs_lo[swz8(row, g)];
            }
#pragma unroll
            for (int mt = 0; mt < 4; ++mt)
#pragma unroll
                for (int nt = 0; nt < 4; ++nt) {
                    acc[mt][nt] = __builtin_amdgcn_mfma_f32_16x16x32_f16(ah[mt], bh[nt], acc[mt][nt], 0, 0, 0);
                    if (need_lo) {
                        acc[mt][nt] = __builtin_amdgcn_mfma_f32_16x16x32_f16(ah[mt], bl[nt], acc[mt][nt], 0, 0, 0);
                        acc[mt][nt] = __builtin_amdgcn_mfma_f32_16x16x32_f16(al[mt], bh[nt], acc[mt][nt], 0, 0, 0);
                    }
                }
        }
        __syncthreads();
    }

    // Epilogue: D row = quad*4+reg (m), col = l15 (n). n -> (h, part, d). Undo W scale (1/64).
    const float inv_s = 1.0f / 64.0f;
#pragma unroll
    for (int nt = 0; nt < 4; ++nt) {
        int n = n0 + wn + nt * 16 + l15;
        float bs = bias[n];
        int h = n / 384;
        int r = n % 384;
        int part = r >> 7;      // 0=q 1=k 2=v (uniform per tile)
        int d = r & 127;
#pragma unroll
        for (int mt = 0; mt < 4; ++mt) {
            int mbase = m0 + wm + mt * 16 + quad * 4;
            int b = mbase >> 11, s = mbase & 2047;
            int bh = b * H_ + h;
            if (part == 2) {
                f16x4 pv;
                pv.x = (f16)(acc[mt][nt].x * inv_s + bs);
                pv.y = (f16)(acc[mt][nt].y * inv_s + bs);
                pv.z = (f16)(acc[mt][nt].z * inv_s + bs);
                pv.w = (f16)(acc[mt][nt].w * inv_s + bs);
                *(f16x4*)&vT[((size_t)bh * 128 + d) * 2048 + s] = pv;   // vT[bh][d][s]
            } else {
                f16* dst = (part == 0) ? qh : kh;
                size_t base = (size_t)bh * 2048 * 128;
#pragma unroll
                for (int reg = 0; reg < 4; ++reg)
                    dst[base + (size_t)(s + reg) * 128 + d] = (f16)(acc[mt][nt][reg] * inv_s + bs);
            }
        }
    }
}

// ---------------------------------------------------------------- flash attention per (bh, 128 q-rows)
__global__ __launch_bounds__(256) void attn(
    const f16* __restrict__ qh, const f16* __restrict__ kh, const f16* __restrict__ vT,
    f16* __restrict__ ao)
{
    __shared__ f16 Ks[128 * 128];   // K tile; reused as P tile
    __shared__ f16 Vts[128 * 128];  // V^T tile: [d][key]
    const int t = threadIdx.x;
    const int w = t >> 6, lane = t & 63, quad = lane >> 4, l15 = lane & 15;
    const int bh = blockIdx.y;
    const int q0 = blockIdx.x * 128;
    const f16* Q  = qh + (size_t)bh * 2048 * 128;
    const f16* Kp = kh + (size_t)bh * 2048 * 128;
    const f16* Vp = vT + (size_t)bh * 128 * 2048;

    // softmax fold: exp(sqrt(128)*s - m) = exp2(C2*s - m2)
    const float C2 = (float)(11.313708498984761 * 1.4426950408889634);

    f16x8 qf[2][4];
#pragma unroll
    for (int mt = 0; mt < 2; ++mt)
#pragma unroll
        for (int ks = 0; ks < 4; ++ks) {
            int row = q0 + w * 32 + mt * 16 + l15;
            qf[mt][ks] = *(const f16x8*)&Q[(size_t)row * 128 + ks * 32 + quad * 8];
        }

    f32x4 o[2][8];
    float mrow[2][4], lrow[2][4];
#pragma unroll
    for (int mt = 0; mt < 2; ++mt) {
#pragma unroll
        for (int dt = 0; dt < 8; ++dt) { o[mt][dt].x = 0.f; o[mt][dt].y = 0.f; o[mt][dt].z = 0.f; o[mt][dt].w = 0.f; }
#pragma unroll
        for (int reg = 0; reg < 4; ++reg) { mrow[mt][reg] = -1e30f; lrow[mt][reg] = 0.f; }
    }

    for (int j = 0; j < 16; ++j) {
        __syncthreads();   // previous iter done with Ks(P)/Vts
#pragma unroll
        for (int i = 0; i < 8; ++i) {
            int c = t + i * 256;             // 0..2047
            int row = c >> 4, g = c & 15;
            *(f16x8*)&Ks[swz16(row, g)]  = *(const f16x8*)&Kp[(size_t)(j * 128 + row) * 128 + g * 8];
            *(f16x8*)&Vts[swz16(row, g)] = *(const f16x8*)&Vp[(size_t)row * 2048 + j * 128 + g * 8];
        }
        __syncthreads();

        // S = Q K^T  (wave: 32 q-rows x 128 keys)
        f32x4 sa[2][8];
#pragma unroll
        for (int mt = 0; mt < 2; ++mt)
#pragma unroll
            for (int nt = 0; nt < 8; ++nt) { sa[mt][nt].x = 0.f; sa[mt][nt].y = 0.f; sa[mt][nt].z = 0.f; sa[mt][nt].w = 0.f; }
#pragma unroll
        for (int ks = 0; ks < 4; ++ks) {
            int g = ks * 4 + quad;
            f16x8 bf[8];
#pragma unroll
            for (int nt = 0; nt < 8; ++nt) { int row = nt * 16 + l15; bf[nt] = *(const f16x8*)&Ks[swz16(row, g)]; }
#pragma unroll
            for (int mt = 0; mt < 2; ++mt)
#pragma unroll
                for (int nt = 0; nt < 8; ++nt)
                    sa[mt][nt] = __builtin_amdgcn_mfma_f32_16x16x32_f16(qf[mt][ks], bf[nt], sa[mt][nt], 0, 0, 0);
        }

        // online softmax (rows live on 16-lane groups; reduce via shfl_xor 1,2,4,8)
        float mnew[2][4], alpha[2][4];
#pragma unroll
        for (int mt = 0; mt < 2; ++mt)
#pragma unroll
            for (int reg = 0; reg < 4; ++reg) {
                float mx = sa[mt][0][reg];
#pragma unroll
                for (int nt = 1; nt < 8; ++nt) mx = fmaxf(mx, sa[mt][nt][reg]);
                mx *= C2;
#pragma unroll
                for (int d = 1; d < 16; d <<= 1) mx = fmaxf(mx, __shfl_xor(mx, d));
                float mn = fmaxf(mrow[mt][reg], mx);
                mnew[mt][reg]  = mn;
                alpha[mt][reg] = exp2f(mrow[mt][reg] - mn);
                mrow[mt][reg]  = mn;
            }
#pragma unroll
        for (int mt = 0; mt < 2; ++mt)
#pragma unroll
            for (int reg = 0; reg < 4; ++reg) {
                float rs = 0.f;
#pragma unroll
                for (int nt = 0; nt < 8; ++nt) {
                    float p = exp2f(sa[mt][nt][reg] * C2 - mnew[mt][reg]);
                    sa[mt][nt][reg] = p;
                    rs += p;
                }
#pragma unroll
                for (int d = 1; d < 16; d <<= 1) rs += __shfl_xor(rs, d);
                lrow[mt][reg] = lrow[mt][reg] * alpha[mt][reg] + rs;
#pragma unroll
                for (int dt = 0; dt < 8; ++dt) o[mt][dt][reg] *= alpha[mt][reg];
            }

        __syncthreads();   // all waves done reading Ks for S
        // write P (f16) into Ks: P[qrow][key]
#pragma unroll
        for (int mt = 0; mt < 2; ++mt)
#pragma unroll
            for (int nt = 0; nt < 8; ++nt) {
                int col = nt * 16 + l15;
#pragma unroll
                for (int reg = 0; reg < 4; ++reg) {
                    int row = w * 32 + mt * 16 + quad * 4 + reg;
                    Ks[row * 128 + (((col >> 3) ^ (row & 15)) << 3) + (col & 7)] = (f16)sa[mt][nt][reg];
                }
            }
        __syncthreads();

        // O += P V   (A = P from Ks, B = V^T rows from Vts)
#pragma unroll
        for (int ks = 0; ks < 4; ++ks) {
            int g = ks * 4 + quad;
            f16x8 pf[2], vf[8];
#pragma unroll
            for (int mt = 0; mt < 2; ++mt) { int row = w * 32 + mt * 16 + l15; pf[mt] = *(const f16x8*)&Ks[swz16(row, g)]; }
#pragma unroll
            for (int dt = 0; dt < 8; ++dt) { int row = dt * 16 + l15; vf[dt] = *(const f16x8*)&Vts[swz16(row, g)]; }
#pragma unroll
            for (int mt = 0; mt < 2; ++mt)
#pragma unroll
                for (int dt = 0; dt < 8; ++dt)
                    o[mt][dt] = __builtin_amdgcn_mfma_f32_16x16x32_f16(pf[mt], vf[dt], o[mt][dt], 0, 0, 0);
        }
    }

    // epilogue: ao[b*2048+s][h*128+d]
    const int b = bh >> 4, h = bh & 15;
#pragma unroll
    for (int mt = 0; mt < 2; ++mt) {
        float inv[4];
#pragma unroll
        for (int reg = 0; reg < 4; ++reg) inv[reg] = 1.0f / lrow[mt][reg];
#pragma unroll
        for (int dt = 0; dt < 8; ++dt) {
            int col = h * 128 + dt * 16 + l15;
#pragma unroll
            for (int reg = 0; reg < 4; ++reg) {
                int srow = q0 + w * 32 + mt * 16 + quad * 4 + reg;
                ao[(size_t)((b << 11) + srow) * 2048 + col] = (f16)(o[mt][dt][reg] * inv[reg]);
            }
        }
    }
}

// ---------------------------------------------------------------- GEMM3: out = ao @ Wproj^T + bproj (fp32 out)
__global__ __launch_bounds__(256) void gemm_proj(
    const f16* __restrict__ A, const f16* __restrict__ W, const float* __restrict__ bias,
    float* __restrict__ out)
{
    __shared__ f16 As[128 * 64];
    __shared__ f16 Bs[128 * 64];
    const int t = threadIdx.x;
    const int w = t >> 6, lane = t & 63, quad = lane >> 4, l15 = lane & 15;
    const int m0 = blockIdx.y * 128, n0 = blockIdx.x * 128;
    const int wm = (w & 1) * 64, wn = (w >> 1) * 64;

    f32x4 acc[4][4];
#pragma unroll
    for (int i = 0; i < 4; ++i)
#pragma unroll
        for (int j = 0; j < 4; ++j) { acc[i][j].x = 0.f; acc[i][j].y = 0.f; acc[i][j].z = 0.f; acc[i][j].w = 0.f; }

    for (int kb = 0; kb < K_ / 64; ++kb) {
        const f16* Ag = A + (size_t)m0 * K_ + kb * 64;
        const f16* Bg = W + (size_t)n0 * K_ + kb * 64;
#pragma unroll
        for (int i = 0; i < 4; ++i) {
            int c = t + i * 256;
            int row = c >> 3, g = c & 7;
            *(f16x8*)&As[swz8(row, g)] = *(const f16x8*)(Ag + (size_t)row * K_ + g * 8);
            *(f16x8*)&Bs[swz8(row, g)] = *(const f16x8*)(Bg + (size_t)row * K_ + g * 8);
        }
        __syncthreads();
#pragma unroll
        for (int ks = 0; ks < 2; ++ks) {
            f16x8 af[4], bf[4];
            int g = ks * 4 + quad;
#pragma unroll
            for (int mt = 0; mt < 4; ++mt) { int row = wm + mt * 16 + l15; af[mt] = *(const f16x8*)&As[swz8(row, g)]; }
#pragma unroll
            for (int nt = 0; nt < 4; ++nt) { int row = wn + nt * 16 + l15; bf[nt] = *(const f16x8*)&Bs[swz8(row, g)]; }
#pragma unroll
            for (int mt = 0; mt < 4; ++mt)
#pragma unroll
                for (int nt = 0; nt < 4; ++nt)
                    acc[mt][nt] = __builtin_amdgcn_mfma_f32_16x16x32_f16(af[mt], bf[nt], acc[mt][nt], 0, 0, 0);
        }
        __syncthreads();
    }

#pragma unroll
    for (int nt = 0; nt < 4; ++nt) {
        int n = n0 + wn + nt * 16 + l15;
        float bs = bias[n];
#pragma unroll
        for (int mt = 0; mt < 4; ++mt) {
            int mbase = m0 + wm + mt * 16 + quad * 4;
#pragma unroll
            for (int reg = 0; reg < 4; ++reg)
                out[(size_t)(mbase + reg) * 2048 + n] = acc[mt][nt][reg] + bs;
        }
    }
}

// ---------------------------------------------------------------- launcher
extern "C" void kernel_launch(void* const* d_in, const int* in_sizes, int n_in,
                              void* d_out, int out_size, void* d_ws, size_t ws_size,
                              hipStream_t stream) {
    const float* query = (const float*)d_in[0];
    // d_in[1]=key, d_in[2]=value are unused by the reference
    const float* Wqkv  = (const float*)d_in[3];
    const float* bqkv  = (const float*)d_in[4];
    const float* Wproj = (const float*)d_in[5];
    const float* bproj = (const float*)d_in[6];
    float* out = (float*)d_out;

    char* ws = (char*)d_ws;
    const size_t MB = 1024ull * 1024ull;
    if (ws_size < 72 * MB) return;  // need 72 MB scratch
    f16* w2  = (f16*)(ws);                 //  8 MB: Wproj fp16
    f16* qh  = (f16*)(ws + 8  * MB);       // 16 MB: q [bh][s][d]
    f16* kh  = (f16*)(ws + 24 * MB);       // 16 MB: k [bh][s][d]
    f16* vT  = (f16*)(ws + 40 * MB);       // 16 MB: v [bh][d][s]
    f16* ao  = (f16*)(ws + 56 * MB);       // 16 MB: attention out [m][E]

    int n;
    n = E_ * E_ / 4;   cvt_f32_f16<<<(n + 255) / 256, 256, 0, stream>>>(Wproj, w2, n);

    gemm_qkv<<<dim3(N1_ / 128, M_ / 128), 256, 0, stream>>>(query, Wqkv, bqkv, qh, kh, vT);
    attn<<<dim3(S_ / 128, B_ * H_), 256, 0, stream>>>(qh, kh, vT, ao);
    gemm_proj<<<dim3(E_ / 128, M_ / 128), 256, 0, stream>>>(ao, w2, bproj, out);
}

// Round 3
// 639.516 us; speedup vs baseline: 1.0526x; 1.0526x over previous
//
#include <hip/hip_runtime.h>

// Problem dims
#define B_  2
#define S_  2048
#define E_  2048
#define H_  16
#define HD_ 128
#define M_  (B_*S_)    // 4096 rows of activations
#define N1_ (3*E_)     // 6144 qkv outputs
#define K_  E_         // 2048 reduction dim

typedef _Float16 f16;
typedef __attribute__((ext_vector_type(8))) _Float16 f16x8;
typedef __attribute__((ext_vector_type(4))) _Float16 f16x4;
typedef __attribute__((ext_vector_type(4))) float    f32x4;
typedef __attribute__((ext_vector_type(4))) float    fv4;

// ---------------------------------------------------------------- helpers
__device__ __forceinline__ void async16(const f16* g, f16* l) {
    __builtin_amdgcn_global_load_lds(
        (const __attribute__((address_space(1))) unsigned int*)g,
        (__attribute__((address_space(3))) unsigned int*)l, 16, 0, 0);
}

// XOR-swizzled LDS granule offset (8-half = 16B granules), 64-half rows (8 granules)
__device__ __forceinline__ int swz8(int row, int g) {
    return row * 64 + ((g ^ (row & 7)) << 3);
}
// 128-half rows (16 granules)
__device__ __forceinline__ int swz16(int row, int g) {
    return row * 128 + ((g ^ (row & 15)) << 3);
}

// Stage a 128-row x 64-half tile (1024 granules) into swz8 LDS layout via
// global_load_lds: LDS dest is linear in lane order; source granule index is
// XOR-permuted per lane so LDS content matches swz8().
__device__ __forceinline__ void stage_swz8(const f16* __restrict__ src, int ldg,
                                           f16* lds, int w, int lane) {
#pragma unroll
    for (int i = 0; i < 4; ++i) {
        int p = (w * 4 + i) * 64 + lane;     // granule 0..1023
        int row = p >> 3, gl = p & 7;
        int gs = gl ^ (row & 7);
        async16(src + (size_t)row * ldg + gs * 8, lds + (size_t)p * 8);
    }
}

// Stage a 128-row x 128-half tile (2048 granules) into swz16 LDS layout.
__device__ __forceinline__ void stage_swz16(const f16* __restrict__ src, int ldg,
                                            f16* lds, int w, int lane) {
#pragma unroll
    for (int i = 0; i < 8; ++i) {
        int p = (w * 8 + i) * 64 + lane;     // granule 0..2047
        int row = p >> 4, gl = p & 15;
        int gs = gl ^ (row & 15);
        async16(src + (size_t)row * ldg + gs * 8, lds + (size_t)p * 8);
    }
}

// split 8 fp32 into fp16 hi + lo (x = hi + lo)
__device__ __forceinline__ void split8(fv4 a0, fv4 a1, float scale, f16x8& hi, f16x8& lo) {
    float x[8] = {a0.x, a0.y, a0.z, a0.w, a1.x, a1.y, a1.z, a1.w};
#pragma unroll
    for (int e = 0; e < 8; ++e) {
        float xs = x[e] * scale;
        f16 h = (f16)xs;
        hi[e] = h;
        lo[e] = (f16)(xs - (float)h);
    }
}

// ---------------------------------------------------------------- prepass kernels
__global__ void split_f32(const float* __restrict__ src, f16* __restrict__ hi,
                          f16* __restrict__ lo, float scale, int n8) {
    int i = blockIdx.x * blockDim.x + threadIdx.x;
    if (i < n8) {
        fv4 a0 = ((const fv4*)src)[2 * i];
        fv4 a1 = ((const fv4*)src)[2 * i + 1];
        f16x8 h, l;
        split8(a0, a1, scale, h, l);
        ((f16x8*)hi)[i] = h;
        ((f16x8*)lo)[i] = l;
    }
}

__global__ void cvt_f32_f16(const float* __restrict__ src, f16* __restrict__ dst, int n4) {
    int i = blockIdx.x * blockDim.x + threadIdx.x;
    if (i < n4) {
        fv4 v = ((const fv4*)src)[i];
        f16x4 h;
        h.x = (f16)v.x; h.y = (f16)v.y; h.z = (f16)v.z; h.w = (f16)v.w;
        ((f16x4*)dst)[i] = h;
    }
}

// ---------------------------------------------------------------- GEMM1: qkv = query @ Wqkv^T + bqkv
// split-fp16 (hi+lo) MFMA for q/k output tiles, hi-only for v tiles.
// W pre-scaled by 64 (undone in epilogue) so W_lo stays fp16-normal.
// AsyncA=true: A pre-split in global, staged via global_load_lds.
// AsyncA=false: A read as fp32 and split in-kernel (ws-constrained fallback).
template <bool AsyncA>
__global__ __launch_bounds__(256) void gemm_qkv(
    const float* __restrict__ A, const f16* __restrict__ A_hi, const f16* __restrict__ A_lo,
    const f16* __restrict__ W_hi, const f16* __restrict__ W_lo, const float* __restrict__ bias,
    f16* __restrict__ qh, f16* __restrict__ kh, f16* __restrict__ vT)
{
    __shared__ f16 As_hi[128 * 64];
    __shared__ f16 As_lo[128 * 64];
    __shared__ f16 Bs_hi[128 * 64];
    __shared__ f16 Bs_lo[128 * 64];
    const int t = threadIdx.x;
    const int w = t >> 6, lane = t & 63, quad = lane >> 4, l15 = lane & 15;
    const int m0 = blockIdx.y * 128, n0 = blockIdx.x * 128;
    const int wm = (w & 1) * 64, wn = (w >> 1) * 64;
    // 384 = 3*128: each 128-wide n-tile is entirely q (0), k (1), or v (2)
    const int tile_part = (n0 % 384) >> 7;
    const bool need_lo = (tile_part != 2);   // v columns don't feed softmax

    f32x4 acc[4][4];
#pragma unroll
    for (int i = 0; i < 4; ++i)
#pragma unroll
        for (int j = 0; j < 4; ++j) { acc[i][j].x = 0.f; acc[i][j].y = 0.f; acc[i][j].z = 0.f; acc[i][j].w = 0.f; }

    for (int kb = 0; kb < K_ / 64; ++kb) {
        // ---- staging
        stage_swz8(W_hi + (size_t)n0 * K_ + kb * 64, K_, Bs_hi, w, lane);
        if (need_lo)
            stage_swz8(W_lo + (size_t)n0 * K_ + kb * 64, K_, Bs_lo, w, lane);
        if (AsyncA) {
            stage_swz8(A_hi + (size_t)m0 * K_ + kb * 64, K_, As_hi, w, lane);
            if (need_lo)
                stage_swz8(A_lo + (size_t)m0 * K_ + kb * 64, K_, As_lo, w, lane);
        } else {
            const float* Ag = A + (size_t)m0 * K_ + kb * 64;
#pragma unroll
            for (int i = 0; i < 4; ++i) {
                int gid = t + i * 256;           // granule id 0..1023
                int row = gid >> 3, g = gid & 7;
                const float* ap = Ag + (size_t)row * K_ + g * 8;
                fv4 a0 = *(const fv4*)ap;
                fv4 a1 = *(const fv4*)(ap + 4);
                f16x8 hi, lo;
                split8(a0, a1, 1.0f, hi, lo);
                *(f16x8*)&As_hi[swz8(row, g)] = hi;
                *(f16x8*)&As_lo[swz8(row, g)] = lo;
            }
        }
        __syncthreads();   // drains vmcnt (global_load_lds) + lgkmcnt

        // ---- compute
#pragma unroll
        for (int ks = 0; ks < 2; ++ks) {
            f16x8 ah[4], al[4], bh[4], bl[4];
            int g = ks * 4 + quad;
#pragma unroll
            for (int mt = 0; mt < 4; ++mt) {
                int row = wm + mt * 16 + l15;
                ah[mt] = *(const f16x8*)&As_hi[swz8(row, g)];
                al[mt] = *(const f16x8*)&As_lo[swz8(row, g)];
            }
#pragma unroll
            for (int nt = 0; nt < 4; ++nt) {
                int row = wn + nt * 16 + l15;
                bh[nt] = *(const f16x8*)&Bs_hi[swz8(row, g)];
                bl[nt] = *(const f16x8*)&Bs_lo[swz8(row, g)];
            }
#pragma unroll
            for (int mt = 0; mt < 4; ++mt)
#pragma unroll
                for (int nt = 0; nt < 4; ++nt) {
                    acc[mt][nt] = __builtin_amdgcn_mfma_f32_16x16x32_f16(ah[mt], bh[nt], acc[mt][nt], 0, 0, 0);
                    if (need_lo) {
                        acc[mt][nt] = __builtin_amdgcn_mfma_f32_16x16x32_f16(ah[mt], bl[nt], acc[mt][nt], 0, 0, 0);
                        acc[mt][nt] = __builtin_amdgcn_mfma_f32_16x16x32_f16(al[mt], bh[nt], acc[mt][nt], 0, 0, 0);
                    }
                }
        }
        __syncthreads();
    }

    // Epilogue: D row = quad*4+reg (m), col = l15 (n). n -> (h, part, d). Undo W scale (1/64).
    const float inv_s = 1.0f / 64.0f;
#pragma unroll
    for (int nt = 0; nt < 4; ++nt) {
        int n = n0 + wn + nt * 16 + l15;
        float bs = bias[n];
        int h = n / 384;
        int r = n % 384;
        int part = r >> 7;      // 0=q 1=k 2=v (uniform per tile)
        int d = r & 127;
#pragma unroll
        for (int mt = 0; mt < 4; ++mt) {
            int mbase = m0 + wm + mt * 16 + quad * 4;
            int b = mbase >> 11, s = mbase & 2047;
            int bh = b * H_ + h;
            if (part == 2) {
                f16x4 pv;
                pv.x = (f16)(acc[mt][nt].x * inv_s + bs);
                pv.y = (f16)(acc[mt][nt].y * inv_s + bs);
                pv.z = (f16)(acc[mt][nt].z * inv_s + bs);
                pv.w = (f16)(acc[mt][nt].w * inv_s + bs);
                *(f16x4*)&vT[((size_t)bh * 128 + d) * 2048 + s] = pv;   // vT[bh][d][s]
            } else {
                f16* dst = (part == 0) ? qh : kh;
                size_t base = (size_t)bh * 2048 * 128;
#pragma unroll
                for (int reg = 0; reg < 4; ++reg)
                    dst[base + (size_t)(s + reg) * 128 + d] = (f16)(acc[mt][nt][reg] * inv_s + bs);
            }
        }
    }
}

// ---------------------------------------------------------------- flash attention per (bh, 128 q-rows)
__global__ __launch_bounds__(256) void attn(
    const f16* __restrict__ qh, const f16* __restrict__ kh, const f16* __restrict__ vT,
    f16* __restrict__ ao)
{
    __shared__ f16 Ks[128 * 128];   // K tile; reused as P tile
    __shared__ f16 Vts[128 * 128];  // V^T tile: [d][key]
    const int t = threadIdx.x;
    const int w = t >> 6, lane = t & 63, quad = lane >> 4, l15 = lane & 15;
    const int bh = blockIdx.y;
    const int q0 = blockIdx.x * 128;
    const f16* Q  = qh + (size_t)bh * 2048 * 128;
    const f16* Kp = kh + (size_t)bh * 2048 * 128;
    const f16* Vp = vT + (size_t)bh * 128 * 2048;

    // softmax fold: exp(sqrt(128)*s - m) = exp2(C2*s - m2)
    const float C2 = (float)(11.313708498984761 * 1.4426950408889634);

    f16x8 qf[2][4];
#pragma unroll
    for (int mt = 0; mt < 2; ++mt)
#pragma unroll
        for (int ks = 0; ks < 4; ++ks) {
            int row = q0 + w * 32 + mt * 16 + l15;
            qf[mt][ks] = *(const f16x8*)&Q[(size_t)row * 128 + ks * 32 + quad * 8];
        }

    f32x4 o[2][8];
    float mrow[2][4], lrow[2][4];
#pragma unroll
    for (int mt = 0; mt < 2; ++mt) {
#pragma unroll
        for (int dt = 0; dt < 8; ++dt) { o[mt][dt].x = 0.f; o[mt][dt].y = 0.f; o[mt][dt].z = 0.f; o[mt][dt].w = 0.f; }
#pragma unroll
        for (int reg = 0; reg < 4; ++reg) { mrow[mt][reg] = -1e30f; lrow[mt][reg] = 0.f; }
    }

    for (int j = 0; j < 16; ++j) {
        __syncthreads();   // previous iter done with Ks(P)/Vts
        stage_swz16(Kp + (size_t)(j * 128) * 128, 128, Ks, w, lane);
        stage_swz16(Vp + j * 128, 2048, Vts, w, lane);
        __syncthreads();   // drains vmcnt

        // S = Q K^T  (wave: 32 q-rows x 128 keys)
        f32x4 sa[2][8];
#pragma unroll
        for (int mt = 0; mt < 2; ++mt)
#pragma unroll
            for (int nt = 0; nt < 8; ++nt) { sa[mt][nt].x = 0.f; sa[mt][nt].y = 0.f; sa[mt][nt].z = 0.f; sa[mt][nt].w = 0.f; }
#pragma unroll
        for (int ks = 0; ks < 4; ++ks) {
            int g = ks * 4 + quad;
            f16x8 bf[8];
#pragma unroll
            for (int nt = 0; nt < 8; ++nt) { int row = nt * 16 + l15; bf[nt] = *(const f16x8*)&Ks[swz16(row, g)]; }
#pragma unroll
            for (int mt = 0; mt < 2; ++mt)
#pragma unroll
                for (int nt = 0; nt < 8; ++nt)
                    sa[mt][nt] = __builtin_amdgcn_mfma_f32_16x16x32_f16(qf[mt][ks], bf[nt], sa[mt][nt], 0, 0, 0);
        }

        // online softmax (rows live on 16-lane groups; reduce via shfl_xor 1,2,4,8)
        float mnew[2][4], alpha[2][4];
#pragma unroll
        for (int mt = 0; mt < 2; ++mt)
#pragma unroll
            for (int reg = 0; reg < 4; ++reg) {
                float mx = sa[mt][0][reg];
#pragma unroll
                for (int nt = 1; nt < 8; ++nt) mx = fmaxf(mx, sa[mt][nt][reg]);
                mx *= C2;
#pragma unroll
                for (int d = 1; d < 16; d <<= 1) mx = fmaxf(mx, __shfl_xor(mx, d));
                float mn = fmaxf(mrow[mt][reg], mx);
                mnew[mt][reg]  = mn;
                alpha[mt][reg] = exp2f(mrow[mt][reg] - mn);
                mrow[mt][reg]  = mn;
            }
#pragma unroll
        for (int mt = 0; mt < 2; ++mt)
#pragma unroll
            for (int reg = 0; reg < 4; ++reg) {
                float rs = 0.f;
#pragma unroll
                for (int nt = 0; nt < 8; ++nt) {
                    float p = exp2f(sa[mt][nt][reg] * C2 - mnew[mt][reg]);
                    sa[mt][nt][reg] = p;
                    rs += p;
                }
#pragma unroll
                for (int d = 1; d < 16; d <<= 1) rs += __shfl_xor(rs, d);
                lrow[mt][reg] = lrow[mt][reg] * alpha[mt][reg] + rs;
#pragma unroll
                for (int dt = 0; dt < 8; ++dt) o[mt][dt][reg] *= alpha[mt][reg];
            }

        __syncthreads();   // all waves done reading Ks for S
        // write P (f16) into Ks: P[qrow][key]
#pragma unroll
        for (int mt = 0; mt < 2; ++mt)
#pragma unroll
            for (int nt = 0; nt < 8; ++nt) {
                int col = nt * 16 + l15;
#pragma unroll
                for (int reg = 0; reg < 4; ++reg) {
                    int row = w * 32 + mt * 16 + quad * 4 + reg;
                    Ks[row * 128 + (((col >> 3) ^ (row & 15)) << 3) + (col & 7)] = (f16)sa[mt][nt][reg];
                }
            }
        __syncthreads();

        // O += P V   (A = P from Ks, B = V^T rows from Vts)
#pragma unroll
        for (int ks = 0; ks < 4; ++ks) {
            int g = ks * 4 + quad;
            f16x8 pf[2], vf[8];
#pragma unroll
            for (int mt = 0; mt < 2; ++mt) { int row = w * 32 + mt * 16 + l15; pf[mt] = *(const f16x8*)&Ks[swz16(row, g)]; }
#pragma unroll
            for (int dt = 0; dt < 8; ++dt) { int row = dt * 16 + l15; vf[dt] = *(const f16x8*)&Vts[swz16(row, g)]; }
#pragma unroll
            for (int mt = 0; mt < 2; ++mt)
#pragma unroll
                for (int dt = 0; dt < 8; ++dt)
                    o[mt][dt] = __builtin_amdgcn_mfma_f32_16x16x32_f16(pf[mt], vf[dt], o[mt][dt], 0, 0, 0);
        }
    }

    // epilogue: ao[b*2048+s][h*128+d]
    const int b = bh >> 4, h = bh & 15;
#pragma unroll
    for (int mt = 0; mt < 2; ++mt) {
        float inv[4];
#pragma unroll
        for (int reg = 0; reg < 4; ++reg) inv[reg] = 1.0f / lrow[mt][reg];
#pragma unroll
        for (int dt = 0; dt < 8; ++dt) {
            int col = h * 128 + dt * 16 + l15;
#pragma unroll
            for (int reg = 0; reg < 4; ++reg) {
                int srow = q0 + w * 32 + mt * 16 + quad * 4 + reg;
                ao[(size_t)((b << 11) + srow) * 2048 + col] = (f16)(o[mt][dt][reg] * inv[reg]);
            }
        }
    }
}

// ---------------------------------------------------------------- GEMM3: out = ao @ Wproj^T + bproj (fp32 out)
__global__ __launch_bounds__(256) void gemm_proj(
    const f16* __restrict__ A, const f16* __restrict__ W, const float* __restrict__ bias,
    float* __restrict__ out)
{
    __shared__ f16 As[128 * 64];
    __shared__ f16 Bs[128 * 64];
    const int t = threadIdx.x;
    const int w = t >> 6, lane = t & 63, quad = lane >> 4, l15 = lane & 15;
    const int m0 = blockIdx.y * 128, n0 = blockIdx.x * 128;
    const int wm = (w & 1) * 64, wn = (w >> 1) * 64;

    f32x4 acc[4][4];
#pragma unroll
    for (int i = 0; i < 4; ++i)
#pragma unroll
        for (int j = 0; j < 4; ++j) { acc[i][j].x = 0.f; acc[i][j].y = 0.f; acc[i][j].z = 0.f; acc[i][j].w = 0.f; }

    for (int kb = 0; kb < K_ / 64; ++kb) {
        stage_swz8(A + (size_t)m0 * K_ + kb * 64, K_, As, w, lane);
        stage_swz8(W + (size_t)n0 * K_ + kb * 64, K_, Bs, w, lane);
        __syncthreads();
#pragma unroll
        for (int ks = 0; ks < 2; ++ks) {
            f16x8 af[4], bf[4];
            int g = ks * 4 + quad;
#pragma unroll
            for (int mt = 0; mt < 4; ++mt) { int row = wm + mt * 16 + l15; af[mt] = *(const f16x8*)&As[swz8(row, g)]; }
#pragma unroll
            for (int nt = 0; nt < 4; ++nt) { int row = wn + nt * 16 + l15; bf[nt] = *(const f16x8*)&Bs[swz8(row, g)]; }
#pragma unroll
            for (int mt = 0; mt < 4; ++mt)
#pragma unroll
                for (int nt = 0; nt < 4; ++nt)
                    acc[mt][nt] = __builtin_amdgcn_mfma_f32_16x16x32_f16(af[mt], bf[nt], acc[mt][nt], 0, 0, 0);
        }
        __syncthreads();
    }

#pragma unroll
    for (int nt = 0; nt < 4; ++nt) {
        int n = n0 + wn + nt * 16 + l15;
        float bs = bias[n];
#pragma unroll
        for (int mt = 0; mt < 4; ++mt) {
            int mbase = m0 + wm + mt * 16 + quad * 4;
#pragma unroll
            for (int reg = 0; reg < 4; ++reg)
                out[(size_t)(mbase + reg) * 2048 + n] = acc[mt][nt][reg] + bs;
        }
    }
}

// ---------------------------------------------------------------- launcher
extern "C" void kernel_launch(void* const* d_in, const int* in_sizes, int n_in,
                              void* d_out, int out_size, void* d_ws, size_t ws_size,
                              hipStream_t stream) {
    const float* query = (const float*)d_in[0];
    // d_in[1]=key, d_in[2]=value unused by the reference
    const float* Wqkv  = (const float*)d_in[3];
    const float* bqkv  = (const float*)d_in[4];
    const float* Wproj = (const float*)d_in[5];
    const float* bproj = (const float*)d_in[6];
    float* out = (float*)d_out;

    char* ws = (char*)d_ws;
    const size_t MB = 1024ull * 1024ull;
    const bool big = (ws_size >= 128 * MB);

    f16 *A_hi, *A_lo, *W_hi, *W_lo, *qh, *kh, *vT, *ao, *w2;
    if (big) {
        A_hi = (f16*)(ws);              // 16 MB (reused as ao after gemm_qkv)
        A_lo = (f16*)(ws + 16 * MB);    // 16 MB
        W_hi = (f16*)(ws + 32 * MB);    // 24 MB
        W_lo = (f16*)(ws + 56 * MB);    // 24 MB (first 8 MB reused as w2)
        qh   = (f16*)(ws + 80 * MB);
        kh   = (f16*)(ws + 96 * MB);
        vT   = (f16*)(ws + 112 * MB);
        ao   = (f16*)(ws);
        w2   = (f16*)(ws + 56 * MB);
    } else {
        if (ws_size < 96 * MB) return;
        A_hi = A_lo = nullptr;
        W_hi = (f16*)(ws);              // 24 MB (first 16 MB reused as ao)
        W_lo = (f16*)(ws + 24 * MB);    // 24 MB (first 8 MB reused as w2)
        qh   = (f16*)(ws + 48 * MB);
        kh   = (f16*)(ws + 64 * MB);
        vT   = (f16*)(ws + 80 * MB);
        ao   = (f16*)(ws);
        w2   = (f16*)(ws + 24 * MB);
    }

    // prepass splits (W scaled by 64; A scale 1)
    if (big)
        split_f32<<<(M_ * K_ / 8 + 255) / 256, 256, 0, stream>>>(query, A_hi, A_lo, 1.0f, M_ * K_ / 8);
    split_f32<<<(N1_ * K_ / 8 + 255) / 256, 256, 0, stream>>>(Wqkv, W_hi, W_lo, 64.0f, N1_ * K_ / 8);

    if (big)
        gemm_qkv<true><<<dim3(N1_ / 128, M_ / 128), 256, 0, stream>>>(query, A_hi, A_lo, W_hi, W_lo, bqkv, qh, kh, vT);
    else
        gemm_qkv<false><<<dim3(N1_ / 128, M_ / 128), 256, 0, stream>>>(query, A_hi, A_lo, W_hi, W_lo, bqkv, qh, kh, vT);

    // Wproj -> f16 (aliases W_lo region; safe: launched after gemm_qkv in-stream)
    cvt_f32_f16<<<(E_ * E_ / 4 + 255) / 256, 256, 0, stream>>>(Wproj, w2, E_ * E_ / 4);

    attn<<<dim3(S_ / 128, B_ * H_), 256, 0, stream>>>(qh, kh, vT, ao);
    gemm_proj<<<dim3(E_ / 128, M_ / 128), 256, 0, stream>>>(ao, w2, bproj, out);
}